// Round 8
// baseline (121.828 us; speedup 1.0000x reference)
//
#include <hip/hip_runtime.h>

typedef __attribute__((ext_vector_type(8)))  __bf16 bvec8;
typedef __attribute__((ext_vector_type(4)))  __bf16 bvec4;
typedef __attribute__((ext_vector_type(16))) float  fvec16;
typedef __attribute__((ext_vector_type(8)))  short  svec8;

// ---- pack W[l][j][k][i] fp32 -> Wp bf16, 32x32x16-frag-ready ----
// unit u = (kt16*16 + it2)*64 + lane ; elem e:
//   K = kt16*16 + (lane>>5)*8 + e ; jk = K>>7 ; l = K&127 ; i = it2*32 + (lane&31)
__global__ __launch_bounds__(256) void pack_w(const float* __restrict__ W,
                                              __bf16* __restrict__ Wp) {
    int u = blockIdx.x * 256 + threadIdx.x;
    if (u >= 73728) return;                   // 72 kt16 * 16 it2 * 64
    int lane = u & 63;
    int it2  = (u >> 6) & 15;
    int kt16 = u >> 10;
    int i  = it2 * 32 + (lane & 31);
    int K0 = kt16 * 16 + ((lane >> 5) << 3);
    bvec8 o;
#pragma unroll
    for (int e = 0; e < 8; ++e) {
        int K  = K0 + e;
        int jk = K >> 7;
        int l  = K & 127;
        int j  = (jk * 11) >> 5;              // jk/3 for jk<9
        int k  = jk - 3 * j;
        o[e] = (__bf16)W[((l * 9 + j * 3 + k) << 9) + i];
    }
    *(bvec8*)&Wp[(size_t)u * 8] = o;
}

// ---- main: block = 1 batch x 256 i (half), 512 thr = 8 waves ----
// bx: b = bx>>1, ih = bx&1. wave wid: wi = wid&3 (i-group of 64), wsn = wid>>2 (s-tile).
// wave: am=2 i-tiles of 32, one s-tile; acc = 2 x fvec16 (32 AGPR).
// MFMA: A = W (row=i), B = activations (col=s); D[i][s] -> direct stores.
// ys[row=(n*3+j)*7+w][l 0..127], 16B-unit swizzle u^=(row&15); row 147 = zeros.
// K-loop: zero barriers; W reg-dbuf (aE/aO, dist-2); bf reg-dbuf (bufA/B, dist-1).
__global__ __launch_bounds__(512, 4) void conv_mfma(
    const float* __restrict__ x, const __bf16* __restrict__ Wp,
    float* __restrict__ out)
{
    __shared__ __bf16 xs[12544];              // [l 0..255][c=r*7+w] 25088 B
    __shared__ __bf16 ys[148 * 128];          // 37888 B

    const int tid  = threadIdx.x;
    const int lane = tid & 63;
    const int l31  = lane & 31;
    const int ls5  = lane >> 5;
    const int wid  = tid >> 6;
    const int wi   = wid & 3;                 // i-group (64 i)
    const int wsn  = wid >> 2;                // s-tile
    const int bx   = blockIdx.x;
    const int b    = bx >> 1;
    const int ih   = bx & 1;                  // i-half

    const float* xb = x + (size_t)b * 12544;
    const char*  WpB = (const char*)Wp;
    const int it2b = ih * 8 + wi * 2;         // base it2 for this wave

    // ---- W reg-dbuf prologue: tiles 0,1 in flight during build ----
    bvec8 aE[2][2], aO[2][2];
    {
        const char* g = WpB + ((size_t)lane << 4);
#pragma unroll
        for (int am = 0; am < 2; ++am)
#pragma unroll
            for (int h = 0; h < 2; ++h) {
                const int unit = h * 16 + it2b + am;
                aE[am][h] = *(const bvec8*)(g + (unit << 10));
                aO[am][h] = *(const bvec8*)(g + 32768 + (unit << 10));
            }
    }

    // ---- pass 1: x (f32) -> xs (bf16), float4-vectorized, coalesced ----
    for (int it = 0; it < 7; ++it) {
        int e4 = it * 512 + tid;
        if (e4 < 3136) {
            const float4 v = ((const float4*)xb)[e4];
            bvec4 pk = { (__bf16)v.x, (__bf16)v.y, (__bf16)v.z, (__bf16)v.w };
            *(bvec4*)&xs[e4 * 4] = pk;
        }
    }
    __syncthreads();

    // ---- pass 2: write-once ys build ----
    // maskA: rA = n+j-1 in [0,7) ; maskB: !(j==0&&n==1) && !(j==2&&n==0), rB=(n+j+5)%7
    for (int it = 0; it < 5; ++it) {
        int up = it * 512 + tid;
        if (up < 2368) {
            int row  = up >> 4;
            int useg = up & 15;
            bvec8 ov;
            if (row >= 147) {
                ov = __builtin_bit_cast(bvec8, (svec8)0);
                row = 147;
            } else {
                int w   = row % 7;
                int njq = row / 7;
                int j   = njq % 3;
                int n   = njq / 3;
                int rA  = n + j - 1;
                bool mA = (unsigned)rA < 7u;
                int rB  = n + j + 5; if (rB >= 7) rB -= 7; if (rB >= 7) rB -= 7;
                bool mB = !((j == 0 && n == 1) || (j == 2 && n == 0));
                int cA  = rA * 7 + w;
                int cB  = rB * 7 + w;
                int l0  = useg * 8;
#pragma unroll
                for (int d = 0; d < 8; ++d) {
                    float fa = mA ? (float)xs[(l0 + d) * 49 + cA] : 0.f;
                    float fb = mB ? (float)xs[(128 + l0 + d) * 49 + cB] : 0.f;
                    ov[d] = (__bf16)(fa + fb);
                }
            }
            *(bvec8*)&ys[(row << 7) + ((useg ^ (row & 15)) << 3)] = ov;
        }
    }

    // ---- per-lane column geometry: s = wsn*32 + l31 ----
    const int s_  = wsn * 32 + l31;
    const int sc  = (s_ < 49) ? s_ : 48;
    const int nq  = sc / 7;
    const int nn21 = nq * 21;
    const int oo   = sc - nq * 7;

    fvec16 acc[2];
#pragma unroll
    for (int am = 0; am < 2; ++am)
#pragma unroll
        for (int r = 0; r < 16; ++r) acc[am][r] = 0.f;

    __syncthreads();   // ys complete; no further barriers

#define GEO(JK, ROWE, RX) {                                                   \
        int j_ = ((JK) * 11) >> 5; int k_ = (JK) - 3 * j_;                    \
        int tw_ = oo + k_ + 5; int w_ = tw_ >= 7 ? tw_ - 7 : tw_;             \
        int row_ = nn21 + j_ * 7 + w_;                                        \
        if ((k_ == 0 && oo == 0) || (k_ == 2 && oo == 6)) row_ = 147;         \
        ROWE = row_ << 7; RX = row_ & 15; }

#define READF(BUF, P, ROWE, RX) {                                             \
        _Pragma("unroll")                                                     \
        for (int h = 0; h < 2; ++h) {                                         \
            int u_ = ((P) * 4 + h * 2 + ls5) ^ (RX);                          \
            BUF[h] = *(const bvec8*)&ys[(ROWE) + (u_ << 3)]; } }

#define MFMA4(BUF, AW) {                                                      \
        __builtin_amdgcn_s_setprio(1);                                        \
        _Pragma("unroll")                                                     \
        for (int h = 0; h < 2; ++h)                                           \
        _Pragma("unroll")                                                     \
        for (int am = 0; am < 2; ++am)                                        \
            acc[am] = __builtin_amdgcn_mfma_f32_32x32x16_bf16(                \
                AW[am][h], BUF[h], acc[am], 0, 0, 0);                         \
        __builtin_amdgcn_s_setprio(0); }

#define PREFW(AW, T) if ((T) < 36) {                                          \
        const char* gp = WpB + ((size_t)(T) << 15) + ((size_t)lane << 4);     \
        _Pragma("unroll")                                                     \
        for (int am = 0; am < 2; ++am)                                        \
        _Pragma("unroll")                                                     \
        for (int h = 0; h < 2; ++h)                                           \
            AW[am][h] = *(const bvec8*)(gp + ((h * 16 + it2b + am) << 10)); }

    int rowE, rx, rowEn, rxn;
    GEO(0, rowE, rx);
    bvec8 bufA[2], bufB[2];
    READF(bufA, 0, rowE, rx);

    for (int jk = 0; jk < 9; ++jk) {
        const int t0 = jk * 4;
        // p0: t0 even -> aE holds tile t0
        READF(bufB, 1, rowE, rx);
        MFMA4(bufA, aE);
        PREFW(aE, t0 + 2);
        // p1
        READF(bufA, 2, rowE, rx);
        MFMA4(bufB, aO);
        PREFW(aO, t0 + 3);
        // p2
        READF(bufB, 3, rowE, rx);
        { int jn = jk < 8 ? jk + 1 : 8; GEO(jn, rowEn, rxn); }
        MFMA4(bufA, aE);
        PREFW(aE, t0 + 4);
        // p3: read p0 of next jk with next geometry
        READF(bufA, 0, rowEn, rxn);
        MFMA4(bufB, aO);
        PREFW(aO, t0 + 5);
        rowE = rowEn; rx = rxn;
    }

#undef GEO
#undef READF
#undef MFMA4
#undef PREFW

    // ---- epilogue: D row=(r&3)+8*(r>>2)+4*ls5 -> i ; col=l31 -> s ----
    const size_t obase = (size_t)b * 25088;   // 512*49
    if (!(wsn == 1 && l31 >= 17)) {           // s < 49
#pragma unroll
        for (int am = 0; am < 2; ++am) {
            const int i0 = ih * 256 + (wi * 2 + am) * 32 + 4 * ls5;
#pragma unroll
            for (int r = 0; r < 16; ++r) {
                int i = i0 + (r & 3) + 8 * (r >> 2);
                out[obase + (size_t)i * 49 + s_] = acc[am][r];
            }
        }
    }
}

extern "C" void kernel_launch(void* const* d_in, const int* in_sizes, int n_in,
                              void* d_out, int out_size, void* d_ws, size_t ws_size,
                              hipStream_t stream) {
    const float* x = (const float*)d_in[0];   // (1024,256,7,7)
    const float* W = (const float*)d_in[1];   // (128,3,3,512)
    float* out = (float*)d_out;               // (1024,512,7,7)
    __bf16* Wp = (__bf16*)d_ws;               // 72*16*64*8 bf16 = 1.18 MB
    (void)in_sizes; (void)n_in; (void)out_size; (void)ws_size;

    hipLaunchKernelGGL(pack_w, dim3(288), dim3(256), 0, stream, W, Wp);
    hipLaunchKernelGGL(conv_mfma, dim3(2048), dim3(512), 0, stream, x, Wp, out);
}

// Round 9
// 113.523 us; speedup vs baseline: 1.0732x; 1.0732x over previous
//
#include <hip/hip_runtime.h>

typedef __attribute__((ext_vector_type(8)))  __bf16 bvec8;
typedef __attribute__((ext_vector_type(4)))  __bf16 bvec4;
typedef __attribute__((ext_vector_type(16))) float  fvec16;
typedef __attribute__((ext_vector_type(8)))  short  svec8;

// ---- pack W[l][j][k][i] fp32 -> Wp bf16, 32x32x16-frag-ready ----
// unit u = (kt16*16 + it2)*64 + lane ; elem e:
//   K = kt16*16 + (lane>>5)*8 + e ; jk = K>>7 ; l = K&127 ; i = it2*32 + (lane&31)
__global__ __launch_bounds__(256) void pack_w(const float* __restrict__ W,
                                              __bf16* __restrict__ Wp) {
    int u = blockIdx.x * 256 + threadIdx.x;
    if (u >= 73728) return;                   // 72 kt16 * 16 it2 * 64
    int lane = u & 63;
    int it2  = (u >> 6) & 15;
    int kt16 = u >> 10;
    int i  = it2 * 32 + (lane & 31);
    int K0 = kt16 * 16 + ((lane >> 5) << 3);
    bvec8 o;
#pragma unroll
    for (int e = 0; e < 8; ++e) {
        int K  = K0 + e;
        int jk = K >> 7;
        int l  = K & 127;
        int j  = (jk * 11) >> 5;              // jk/3 for jk<9
        int k  = jk - 3 * j;
        o[e] = (__bf16)W[((l * 9 + j * 3 + k) << 9) + i];
    }
    *(bvec8*)&Wp[(size_t)u * 8] = o;
}

// ---- main: block = 2 batches x 256 i, 512 thr = 8 waves ----
// bx: b0 = (bx>>1)*2, ih = bx&1. wave: wi = wid&3 (i-group of 64), msel = wid>>2 (s-half).
// wave tiles: am(2 i-units of 32) x bb(2 batches) -> acc[2][2], W frags shared across bb.
// ys dedup: row content depends only on t=n+j (+2 A-only specials + zero row):
//   rows 0..62: t*7+w  = [1<=t<=7]*xA[t-1,w] + xB[(t+5)%7,w]
//   rows 63..69: xA[0,w] (n=1,j=0) ; rows 70..76: xA[1,w] (n=0,j=2) ; row 77: zeros
// per-batch stride 78 rows; 16B-unit swizzle u^=(row&15).
__global__ __launch_bounds__(512, 4) void conv_mfma(
    const float* __restrict__ x, const __bf16* __restrict__ Wp,
    float* __restrict__ out)
{
    __shared__ __bf16 xs[12544];              // [ch 0..255][c=r*7+w] 25088 B
    __shared__ __bf16 ys[156 * 128];          // 2 batches x 78 rows x 128 l = 39936 B

    const int tid  = threadIdx.x;
    const int lane = tid & 63;
    const int l31  = lane & 31;
    const int ls5  = lane >> 5;
    const int wid  = tid >> 6;
    const int wi   = wid & 3;                 // i-group (64 i)
    const int msel = wid >> 2;                // s-half
    const int bx   = blockIdx.x;
    const int b0   = (bx >> 1) << 1;
    const int ih   = bx & 1;                  // i-half
    const int it2b = ih * 8 + wi * 2;

    const float* xb = x + (size_t)b0 * 12544;
    const char*  WpB = (const char*)Wp;

    // ---- W reg-dbuf prologue: tiles 0,1 in flight during build ----
    bvec8 aE[2][2], aO[2][2];
    {
        const char* g = WpB + ((size_t)lane << 4);
#pragma unroll
        for (int am = 0; am < 2; ++am)
#pragma unroll
            for (int h = 0; h < 2; ++h) {
                const int unit = h * 16 + it2b + am;
                aE[am][h] = *(const bvec8*)(g + (unit << 10));
                aO[am][h] = *(const bvec8*)(g + 32768 + (unit << 10));
            }
    }

    // ---- build ys for both batches (shared xs buffer, sequential) ----
    for (int bb = 0; bb < 2; ++bb) {
        // stage x[b0+bb] f32 -> xs bf16, float4-vectorized
        for (int it = 0; it < 7; ++it) {
            int e4 = it * 512 + tid;
            if (e4 < 3136) {
                const float4 v = ((const float4*)(xb + bb * 12544))[e4];
                bvec4 pk = { (__bf16)v.x, (__bf16)v.y, (__bf16)v.z, (__bf16)v.w };
                *(bvec4*)&xs[e4 * 4] = pk;
            }
        }
        __syncthreads();
        // build 78 dedup'd rows (write-once b128)
        for (int it = 0; it < 3; ++it) {
            int up = it * 512 + tid;
            if (up < 1248) {
                int row  = up >> 4;
                int useg = up & 15;
                int l0   = useg * 8;
                bvec8 ov;
                if (row == 77) {
                    ov = __builtin_bit_cast(bvec8, (svec8)0);
                } else if (row < 63) {
                    int t = row / 7, w = row - t * 7;
                    int tb = t + 5; if (tb >= 7) tb -= 7;
                    int cB = tb * 7 + w;
                    bool mA = (t >= 1) && (t <= 7);
                    int cA = mA ? (t - 1) * 7 + w : 0;
#pragma unroll
                    for (int d = 0; d < 8; ++d) {
                        float fa = mA ? (float)xs[(l0 + d) * 49 + cA] : 0.f;
                        float fb = (float)xs[(128 + l0 + d) * 49 + cB];
                        ov[d] = (__bf16)(fa + fb);
                    }
                } else if (row < 70) {
                    int w = row - 63;
#pragma unroll
                    for (int d = 0; d < 8; ++d) ov[d] = xs[(l0 + d) * 49 + w];
                } else {
                    int w = row - 70;
#pragma unroll
                    for (int d = 0; d < 8; ++d) ov[d] = xs[(l0 + d) * 49 + 7 + w];
                }
                *(bvec8*)&ys[((bb * 78 + row) << 7) + ((useg ^ (row & 15)) << 3)] = ov;
            }
        }
        __syncthreads();
    }

    // ---- per-lane column geometry: s = msel*32 + l31 ----
    const int s_  = msel * 32 + l31;
    const int sc  = (s_ < 49) ? s_ : 48;
    const int nq  = sc / 7;
    const int oo  = sc - nq * 7;

    fvec16 acc[2][2];
#pragma unroll
    for (int am = 0; am < 2; ++am)
#pragma unroll
        for (int bb = 0; bb < 2; ++bb)
#pragma unroll
            for (int r = 0; r < 16; ++r) acc[am][bb][r] = 0.f;

    // ---- K-loop: zero barriers; W reg-dbuf dist-2; 8 MFMA per step ----
    for (int jk = 0; jk < 9; ++jk) {
        const int j = (jk * 11) >> 5;
        const int k = jk - 3 * j;
        int tw = oo + k + 5;
        int w  = tw >= 7 ? tw - 7 : tw;                  // (o+k+5)%7
        int row = (nq + j) * 7 + w;
        if (nq == 1 && j == 0) row = 63 + w;             // S1: xA[0,w] only
        if (nq == 0 && j == 2) row = 70 + w;             // S2: xA[1,w] only
        if ((k == 0 && oo == 0) || (k == 2 && oo == 6)) row = 77;  // zero row
        const int rowE = row << 7;
        const int rx   = row & 15;
#pragma unroll
        for (int p = 0; p < 4; ++p) {
            const int t = jk * 4 + p;
            bvec8 bf[2][2];                              // [bb][h]
#pragma unroll
            for (int h = 0; h < 2; ++h) {
                int u = (p * 4 + h * 2 + ls5) ^ rx;
                bf[0][h] = *(const bvec8*)&ys[rowE + (u << 3)];
                bf[1][h] = *(const bvec8*)&ys[9984 + rowE + (u << 3)];
            }
            __builtin_amdgcn_s_setprio(1);
            if ((p & 1) == 0) {
#pragma unroll
                for (int h = 0; h < 2; ++h)
#pragma unroll
                    for (int am = 0; am < 2; ++am)
#pragma unroll
                        for (int bb = 0; bb < 2; ++bb)
                            acc[am][bb] = __builtin_amdgcn_mfma_f32_32x32x16_bf16(
                                aE[am][h], bf[bb][h], acc[am][bb], 0, 0, 0);
            } else {
#pragma unroll
                for (int h = 0; h < 2; ++h)
#pragma unroll
                    for (int am = 0; am < 2; ++am)
#pragma unroll
                        for (int bb = 0; bb < 2; ++bb)
                            acc[am][bb] = __builtin_amdgcn_mfma_f32_32x32x16_bf16(
                                aO[am][h], bf[bb][h], acc[am][bb], 0, 0, 0);
            }
            __builtin_amdgcn_s_setprio(0);
            // prefetch tile t+2 into the buffer just consumed
            if (t + 2 < 36) {
                const char* g = WpB + ((size_t)(t + 2) << 15) + ((size_t)lane << 4);
                if ((p & 1) == 0) {
#pragma unroll
                    for (int am = 0; am < 2; ++am)
#pragma unroll
                        for (int h = 0; h < 2; ++h)
                            aE[am][h] = *(const bvec8*)(g + ((h * 16 + it2b + am) << 10));
                } else {
#pragma unroll
                    for (int am = 0; am < 2; ++am)
#pragma unroll
                        for (int h = 0; h < 2; ++h)
                            aO[am][h] = *(const bvec8*)(g + ((h * 16 + it2b + am) << 10));
                }
            }
        }
    }

    // ---- epilogue: D row=(r&3)+8*(r>>2)+4*ls5 -> i ; col=l31 -> s ----
    if (!(msel == 1 && l31 >= 17)) {          // s < 49
#pragma unroll
        for (int am = 0; am < 2; ++am) {
            const int i0 = ih * 256 + (wi * 2 + am) * 32 + 4 * ls5;
#pragma unroll
            for (int bb = 0; bb < 2; ++bb) {
                const size_t ob = (size_t)(b0 + bb) * 25088;
#pragma unroll
                for (int r = 0; r < 16; ++r) {
                    int i = i0 + (r & 3) + 8 * (r >> 2);
                    out[ob + (size_t)i * 49 + s_] = acc[am][bb][r];
                }
            }
        }
    }
}

extern "C" void kernel_launch(void* const* d_in, const int* in_sizes, int n_in,
                              void* d_out, int out_size, void* d_ws, size_t ws_size,
                              hipStream_t stream) {
    const float* x = (const float*)d_in[0];   // (1024,256,7,7)
    const float* W = (const float*)d_in[1];   // (128,3,3,512)
    float* out = (float*)d_out;               // (1024,512,7,7)
    __bf16* Wp = (__bf16*)d_ws;               // 72*16*64*8 bf16 = 1.18 MB
    (void)in_sizes; (void)n_in; (void)out_size; (void)ws_size;

    hipLaunchKernelGGL(pack_w, dim3(288), dim3(256), 0, stream, W, Wp);
    hipLaunchKernelGGL(conv_mfma, dim3(1024), dim3(512), 0, stream, x, Wp, out);
}

// Round 10
// 102.211 us; speedup vs baseline: 1.1919x; 1.1107x over previous
//
#include <hip/hip_runtime.h>

typedef __attribute__((ext_vector_type(8)))  __bf16 bvec8;
typedef __attribute__((ext_vector_type(4)))  __bf16 bvec4;
typedef __attribute__((ext_vector_type(16))) float  fvec16;
typedef __attribute__((ext_vector_type(8)))  short  svec8;

// ---- pack W[l][j][k][i] fp32 -> Wp bf16, wave-contiguous 32x32x16 frags ----
// unit u: lane=u&63, f=(u>>6)&7 (am=f&3, h=f>>2), wi=(u>>9)&3, t=u>>11 (0..35)
// content: i=(wi*4+am)*32+(lane&31), K=(2t+h)*16+(lane>>5)*8+e ; K=jk*128+l
__global__ __launch_bounds__(256) void pack_w(const float* __restrict__ W,
                                              __bf16* __restrict__ Wp) {
    int u = blockIdx.x * 256 + threadIdx.x;
    if (u >= 73728) return;                   // 36 t * 4 wi * 8 f * 64 lanes
    int lane = u & 63;
    int f    = (u >> 6) & 7;
    int wi   = (u >> 9) & 3;
    int t    = u >> 11;
    int am = f & 3, h = f >> 2;
    int i  = ((wi * 4 + am) << 5) + (lane & 31);
    int K0 = ((2 * t + h) << 4) + ((lane >> 5) << 3);
    bvec8 o;
#pragma unroll
    for (int e = 0; e < 8; ++e) {
        int K  = K0 + e;
        int jk = K >> 7;
        int l  = K & 127;
        int j  = (jk * 11) >> 5;              // jk/3 for jk<9
        int k  = jk - 3 * j;
        o[e] = (__bf16)W[((l * 9 + j * 3 + k) << 9) + i];
    }
    *(bvec8*)&Wp[(size_t)u * 8] = o;
}

// ---- main: block = 2 batches x 512 i x 64 s, 512 thr = 8 waves ----
// wave (wi = wid&3, ws = wid>>2): am4 (128 i) x sn1 (32 s) x bb2 -> acc[4][2].
// ys dedup (per batch, 78 rows x 128 l):
//   rows 0..62: t=n+j: [1<=t<=7]*xA[t-1,w] + xB[(t+5)%7,w]
//   63..69: xA[0,w] (n=1,j=0) ; 70..76: xA[1,w] (n=0,j=2) ; 77: zeros
// 16B-unit swizzle u^=(row&15).
// K-loop: barrier-free; W reg-dbuf dist-2 (aE/aO); bf reg-dbuf dist-1 (bfA/bfB).
__global__ __launch_bounds__(512, 2) void conv_mfma(
    const float* __restrict__ x, const __bf16* __restrict__ Wp,
    float* __restrict__ out)
{
    __shared__ __align__(16) char smem[65024];
    __bf16* xs = (__bf16*)smem;               // 25088 B (build)
    __bf16* ys = (__bf16*)(smem + 25088);     // 39936 B (2 x 78 x 256 B)
    float*  T  = (float*)smem;                // 53248 B (epilogue, stride 52)

    const int tid  = threadIdx.x;
    const int lane = tid & 63;
    const int l31  = lane & 31;
    const int ls5  = lane >> 5;
    const int wid  = tid >> 6;
    const int wi   = wid & 3;                 // i-group (128 i)
    const int ws   = wid >> 2;                // s-tile (32 s)
    const int b0   = blockIdx.x * 2;

    const float* xb  = x + (size_t)b0 * 12544;
    const char*  WpB = (const char*)Wp;

    // ---- W prologue: tiles 0,1 into regs (land during build) ----
    bvec8 aE[4][2], aO[4][2];
    {
        const char* g0 = WpB + (size_t)wi * 8192 + ((size_t)lane << 4);
#pragma unroll
        for (int am = 0; am < 4; ++am)
#pragma unroll
            for (int h = 0; h < 2; ++h) {
                aE[am][h] = *(const bvec8*)(g0 + ((h * 4 + am) << 10));
                aO[am][h] = *(const bvec8*)(g0 + 32768 + ((h * 4 + am) << 10));
            }
    }

    // ---- build ys for both batches ----
#pragma unroll
    for (int bb = 0; bb < 2; ++bb) {
        for (int it = 0; it < 7; ++it) {
            int e4 = it * 512 + tid;
            if (e4 < 3136) {
                const float4 v = ((const float4*)(xb + bb * 12544))[e4];
                bvec4 pk = { (__bf16)v.x, (__bf16)v.y, (__bf16)v.z, (__bf16)v.w };
                *(bvec4*)&xs[e4 * 4] = pk;
            }
        }
        __syncthreads();
        for (int it = 0; it < 3; ++it) {
            int up = it * 512 + tid;
            if (up < 1248) {
                int row  = up >> 4;
                int useg = up & 15;
                int l0   = useg * 8;
                bvec8 ov;
                if (row == 77) {
                    ov = __builtin_bit_cast(bvec8, (svec8)0);
                } else if (row < 63) {
                    int t = row / 7, w = row - t * 7;
                    int tb = t + 5; if (tb >= 7) tb -= 7;
                    int cB = tb * 7 + w;
                    bool mA = (t >= 1) && (t <= 7);
                    int cA = mA ? (t - 1) * 7 + w : 0;
#pragma unroll
                    for (int d = 0; d < 8; ++d) {
                        float fa = mA ? (float)xs[(l0 + d) * 49 + cA] : 0.f;
                        float fb = (float)xs[(128 + l0 + d) * 49 + cB];
                        ov[d] = (__bf16)(fa + fb);
                    }
                } else if (row < 70) {
                    int w = row - 63;
#pragma unroll
                    for (int d = 0; d < 8; ++d) ov[d] = xs[(l0 + d) * 49 + w];
                } else {
                    int w = row - 70;
#pragma unroll
                    for (int d = 0; d < 8; ++d) ov[d] = xs[(l0 + d) * 49 + 7 + w];
                }
                *(bvec8*)&ys[((bb * 78 + row) << 7) + ((useg ^ (row & 15)) << 3)] = ov;
            }
        }
        __syncthreads();
    }

    // ---- per-lane column geometry: s = ws*32 + l31 ----
    const int s_ = ws * 32 + l31;
    const int sc = (s_ < 49) ? s_ : 48;
    const int nq = sc / 7;
    const int oo = sc - nq * 7;

    fvec16 acc[4][2];
#pragma unroll
    for (int am = 0; am < 4; ++am)
#pragma unroll
        for (int bb = 0; bb < 2; ++bb)
#pragma unroll
            for (int r = 0; r < 16; ++r) acc[am][bb][r] = 0.f;

#define GEO(JK, ROWE, RX) {                                                   \
        int j_ = ((JK) * 11) >> 5; int k_ = (JK) - 3 * j_;                    \
        int tw_ = oo + k_ + 5; int w_ = tw_ >= 7 ? tw_ - 7 : tw_;             \
        int row_ = (nq + j_) * 7 + w_;                                        \
        if (nq == 1 && j_ == 0) row_ = 63 + w_;                               \
        if (nq == 0 && j_ == 2) row_ = 70 + w_;                               \
        if ((k_ == 0 && oo == 0) || (k_ == 2 && oo == 6)) row_ = 77;          \
        ROWE = row_ << 7; RX = row_ & 15; }

#define READF(DST, P, ROWE, RX) {                                             \
        _Pragma("unroll")                                                     \
        for (int h_ = 0; h_ < 2; ++h_) {                                      \
            int u_ = ((P) * 4 + h_ * 2 + ls5) ^ (RX);                         \
            DST[0][h_] = *(const bvec8*)&ys[(ROWE) + (u_ << 3)];              \
            DST[1][h_] = *(const bvec8*)&ys[9984 + (ROWE) + (u_ << 3)]; } }

#define MFMA16(AW, BF) {                                                      \
        __builtin_amdgcn_s_setprio(1);                                        \
        _Pragma("unroll")                                                     \
        for (int h_ = 0; h_ < 2; ++h_)                                        \
        _Pragma("unroll")                                                     \
        for (int am_ = 0; am_ < 4; ++am_)                                     \
        _Pragma("unroll")                                                     \
        for (int bb_ = 0; bb_ < 2; ++bb_)                                     \
            acc[am_][bb_] = __builtin_amdgcn_mfma_f32_32x32x16_bf16(          \
                AW[am_][h_], BF[bb_][h_], acc[am_][bb_], 0, 0, 0);            \
        __builtin_amdgcn_s_setprio(0); }

#define PREFW(AW, TT) {                                                       \
        const char* gp_ = WpB + (size_t)((TT) * 4 + wi) * 8192                \
                          + ((size_t)lane << 4);                              \
        _Pragma("unroll")                                                     \
        for (int am_ = 0; am_ < 4; ++am_)                                     \
        _Pragma("unroll")                                                     \
        for (int h_ = 0; h_ < 2; ++h_)                                        \
            AW[am_][h_] = *(const bvec8*)(gp_ + ((h_ * 4 + am_) << 10)); }

    // ---- K-loop: 36 steps (9 jk x 4), barrier-free, dual reg-dbuf ----
    int rowE, rx, rowEn, rxn;
    GEO(0, rowE, rx);
    bvec8 bfA[2][2], bfB[2][2];
    READF(bfA, 0, rowE, rx);

    for (int jk = 0; jk < 9; ++jk) {
        // p=0 (t=4jk, even -> aE)
        READF(bfB, 1, rowE, rx);
        MFMA16(aE, bfA);
        PREFW(aE, 4 * jk + 2);                 // always < 36
        // p=1
        READF(bfA, 2, rowE, rx);
        MFMA16(aO, bfB);
        PREFW(aO, 4 * jk + 3);                 // always < 36
        // p=2
        { int jn = jk < 8 ? jk + 1 : 8; GEO(jn, rowEn, rxn); }
        READF(bfB, 3, rowE, rx);
        MFMA16(aE, bfA);
        if (jk < 8) PREFW(aE, 4 * jk + 4);
        // p=3: prefetch next-jk p0
        READF(bfA, 0, rowEn, rxn);
        MFMA16(aO, bfB);
        if (jk < 8) PREFW(aO, 4 * jk + 5);
        rowE = rowEn; rx = rxn;
    }

#undef GEO
#undef READF
#undef MFMA16
#undef PREFW

    // ---- epilogue: acc -> T (LDS) -> linear coalesced stores ----
    // D: row=(r&3)+8*(r>>2)+4*ls5 -> i ; col=l31 -> s
#pragma unroll
    for (int pass = 0; pass < 4; ++pass) {
        const int bb = pass >> 1, ih = pass & 1;
        __syncthreads();
        if ((wi >> 1) == ih && s_ < 49) {
            const int irb = (wi & 1) * 128 + 4 * ls5;
#pragma unroll
            for (int am = 0; am < 4; ++am)
#pragma unroll
                for (int r = 0; r < 16; ++r) {
                    int ir = irb + am * 32 + (r & 3) + 8 * (r >> 2);
                    T[ir * 52 + s_] = acc[am][bb][r];
                }
        }
        __syncthreads();
        const size_t ob = (size_t)(b0 + bb) * 25088 + (size_t)ih * 12544;
        for (int it = 0; it < 25; ++it) {
            int idx = it * 512 + tid;
            if (idx < 12544) {
                int ir = idx / 49;
                int s  = idx - ir * 49;
                out[ob + idx] = T[ir * 52 + s];
            }
        }
    }
}

extern "C" void kernel_launch(void* const* d_in, const int* in_sizes, int n_in,
                              void* d_out, int out_size, void* d_ws, size_t ws_size,
                              hipStream_t stream) {
    const float* x = (const float*)d_in[0];   // (1024,256,7,7)
    const float* W = (const float*)d_in[1];   // (128,3,3,512)
    float* out = (float*)d_out;               // (1024,512,7,7)
    __bf16* Wp = (__bf16*)d_ws;               // 73728*8 bf16 = 1.18 MB
    (void)in_sizes; (void)n_in; (void)out_size; (void)ws_size;

    hipLaunchKernelGGL(pack_w, dim3(288), dim3(256), 0, stream, W, Wp);
    hipLaunchKernelGGL(conv_mfma, dim3(512), dim3(512), 0, stream, x, Wp, out);
}